// Round 10
// baseline (484.821 us; speedup 1.0000x reference)
//
#include <hip/hip_runtime.h>
#include <hip/hip_bf16.h>
#include <stdint.h>

#define L_DIM 1024
#define B_DIM 32
#define D_DIM 1024
#define M_DIM (L_DIM * B_DIM)        // 32768 GEMM rows
#define N3_DIM (3 * D_DIM)           // 3072 GEMM cols (u0 | f | r regions)
#define K_DIM D_DIM                  // 1024
#define LBD ((int64_t)L_DIM * B_DIM * D_DIM)  // 33554432
#define NBD (B_DIM * D_DIM)          // 32768 chains
#define NCHUNK 32
#define CLEN 32

// GEMM tiling: m97 geometry + swizzle + TLP (round-7 proven)
#define BM 128
#define BN 128
#define BK 64
#define NMT (M_DIM / BM)   // 256
#define NNT (N3_DIM / BN)  // 24
#define NKT (K_DIM / BK)   // 16

typedef __bf16 bf16_t;
typedef bf16_t bf16x8 __attribute__((ext_vector_type(8)));
typedef float f32x4 __attribute__((ext_vector_type(4)));
typedef unsigned short ushort8v __attribute__((ext_vector_type(8)));

// RTNE fp32 -> bf16 bits
__device__ __forceinline__ unsigned short f2bf(float f) {
    union { float f; unsigned u; } v; v.f = f;
    unsigned u = v.u;
    u += 0x7FFFu + ((u >> 16) & 1u);
    return (unsigned short)(u >> 16);
}
__device__ __forceinline__ float bf2f(unsigned short h) {
    union { unsigned u; float f; } v; v.u = ((unsigned)h) << 16;
    return v.f;
}

// ---------------- fused converts: x fp32->bf16 (blocks 0..4095), weight permute (blocks 4096..4863) ----------------
__global__ void cvt_kernel(const float* __restrict__ x, unsigned short* __restrict__ xb,
                           const float* __restrict__ w, unsigned short* __restrict__ wT) {
    __shared__ float tile[64][65];
    int bid = blockIdx.x;
    if (bid < 4096) {
        int64_t i0 = ((int64_t)bid * blockDim.x + threadIdx.x) * 8;
        const int64_t stride = (int64_t)4096 * 256 * 8;   // covers LBD in 4 iters
        for (int64_t i = i0; i < LBD; i += stride) {
            float4 v0 = *reinterpret_cast<const float4*>(x + i);
            float4 v1 = *reinterpret_cast<const float4*>(x + i + 4);
            ushort8v o;
            o[0] = f2bf(v0.x); o[1] = f2bf(v0.y); o[2] = f2bf(v0.z); o[3] = f2bf(v0.w);
            o[4] = f2bf(v1.x); o[5] = f2bf(v1.y); o[6] = f2bf(v1.z); o[7] = f2bf(v1.w);
            *reinterpret_cast<ushort8v*>(xb + i) = o;
        }
    } else {
        int wb = bid - 4096;            // 768 = 3(k) * 16(o-tiles) * 16(i-tiles)
        int k  = wb >> 8;
        int o0 = ((wb >> 4) & 15) * 64;
        int i0 = (wb & 15) * 64;
        int t = threadIdx.x;
        {
            int o = t & 63, ib = t >> 6;
            #pragma unroll
            for (int it = 0; it < 16; ++it) {
                int i = ib + it * 4;
                tile[o][i] = w[((int64_t)(i0 + i) * 1024 + (o0 + o)) * 3 + k];
            }
        }
        __syncthreads();
        {
            int i = t & 63, ob = t >> 6;
            #pragma unroll
            for (int ot = 0; ot < 16; ++ot) {
                int o = ob + ot * 4;
                wT[(int64_t)(k * 1024 + o0 + o) * 1024 + (i0 + i)] = f2bf(tile[o][i]);
            }
        }
    }
}

// ---------------- GEMM: m97 2-barrier loop, 128x128, 4 waves, swizzled LDS, XCD nt-banding ----------------
__device__ __forceinline__ void gload_lds16(const void* g, void* l) {
    __builtin_amdgcn_global_load_lds(
        (const __attribute__((address_space(1))) unsigned int*)g,
        (__attribute__((address_space(3))) unsigned int*)l,
        16, 0, 0);
}

__global__ __launch_bounds__(256, 4) void gemm_kernel(
    const unsigned short* __restrict__ A,    // [32768][1024] bf16 bits
    const unsigned short* __restrict__ Bt,   // [3072][1024] bf16 bits
    const float* __restrict__ bias,          // [2048]
    float* __restrict__ u0_out,              // d_out + LBD: u0 fp32 (fallback path)
    unsigned short* __restrict__ fb,         // ws: f bf16
    unsigned short* __restrict__ rb,         // ws: r bf16
    unsigned short* __restrict__ u0b,        // ws: u0 bf16 (fast path) or null
    int useU0b)
{
    // single contiguous LDS block: a_tile | b_tile during K-loop; reused as epilogue stage
    __shared__ __align__(16) unsigned short smem[2 * 128 * 64];
    unsigned short* a_tile = smem;
    unsigned short* b_tile = smem + 128 * 64;

    int bid = blockIdx.x;
    int xcd = bid & 7, local = bid >> 3;           // 768 blocks per XCD
    int nt = xcd * 3 + (local % 3);
    int mt = local / 3;
    int m0 = mt * BM, n0 = nt * BN;

    int tid = threadIdx.x;
    int w = tid >> 6, lane = tid & 63;
    int wm = w >> 1;
    int wr = wm * 64, wc = (w & 1) * 64;           // 2x2 wave grid, 64x64 per wave
    int l15 = lane & 15, l4 = lane >> 4;
    int pcx = l15 & 7;                             // read-side XOR (row&7)

    int sr = lane >> 3;                            // row within 8-row group (= row&7)
    int sc = ((lane & 7) ^ sr) << 3;               // swizzled 16B chunk in bf16 elems
    const unsigned short* Abase = A  + (int64_t)(m0 + sr) * K_DIM + sc;
    const unsigned short* Bbase = Bt + (int64_t)(n0 + sr) * K_DIM + sc;

    f32x4 acc[4][4];
    #pragma unroll
    for (int i = 0; i < 4; ++i)
        #pragma unroll
        for (int j = 0; j < 4; ++j) acc[i][j] = (f32x4){0.f, 0.f, 0.f, 0.f};

    for (int kt = 0; kt < NKT; ++kt) {
        int k0 = kt * BK;
        __syncthreads();
        #pragma unroll
        for (int i = 0; i < 4; ++i) {
            int r0 = (i * 4 + w) * 8;
            gload_lds16(Abase + (int64_t)r0 * K_DIM + k0, &a_tile[r0 * 64]);
            gload_lds16(Bbase + (int64_t)r0 * K_DIM + k0, &b_tile[r0 * 64]);
        }
        __syncthreads();

        #pragma unroll
        for (int ks = 0; ks < 2; ++ks) {
            int pc = ((ks * 4 + l4) ^ pcx) << 3;
            bf16x8 af[4], bf[4];
            #pragma unroll
            for (int im = 0; im < 4; ++im)
                af[im] = *reinterpret_cast<const bf16x8*>(&a_tile[(wr + im * 16 + l15) * 64 + pc]);
            #pragma unroll
            for (int jn = 0; jn < 4; ++jn)
                bf[jn] = *reinterpret_cast<const bf16x8*>(&b_tile[(wc + jn * 16 + l15) * 64 + pc]);
            #pragma unroll
            for (int im = 0; im < 4; ++im)
                #pragma unroll
                for (int jn = 0; jn < 4; ++jn)
                    acc[im][jn] = __builtin_amdgcn_mfma_f32_16x16x32_bf16(
                        af[im], bf[jn], acc[im][jn], 0, 0, 0);
        }
    }

    int region = n0 >> 10;

    if (region == 0 && !useU0b) {
        // fallback: fp32 u0 scatter (rare path)
        #pragma unroll
        for (int im = 0; im < 4; ++im) {
            #pragma unroll
            for (int jn = 0; jn < 4; ++jn) {
                f32x4 v = acc[im][jn];
                int row0 = m0 + wr + im * 16 + l4 * 4;
                int col  = (n0 + wc + jn * 16 + l15) & 1023;
                #pragma unroll
                for (int jj = 0; jj < 4; ++jj)
                    u0_out[(int64_t)(row0 + jj) * 1024 + col] = v[jj];
            }
        }
        return;
    }

    // LDS-staged bf16 epilogue: full 128B-line coalesced stores
    unsigned short* dstb = (region == 0) ? u0b : (region == 1 ? fb : rb);
    int bofs = (region == 2) ? 1024 : 0;
    // ep[64][136] over smem (17408B <= 32768B); pad keeps LDS access <=2-way
    unsigned short (*ep)[136] = reinterpret_cast<unsigned short (*)[136]>(smem);

    #pragma unroll
    for (int p = 0; p < 2; ++p) {
        __syncthreads();                 // prior pass's readers (or K-loop) done
        if (wm == p) {
            #pragma unroll
            for (int im = 0; im < 4; ++im) {
                #pragma unroll
                for (int jn = 0; jn < 4; ++jn) {
                    f32x4 v = acc[im][jn];
                    int col  = wc + jn * 16 + l15;          // 0..127
                    int gcol = (n0 + col) & 1023;
                    #pragma unroll
                    for (int jj = 0; jj < 4; ++jj) {
                        float val = v[jj];
                        unsigned short us;
                        if (region == 0) us = f2bf(val);
                        else             us = f2bf(1.0f / (1.0f + __expf(-(val + bias[bofs + gcol]))));
                        ep[im * 16 + l4 * 4 + jj][col] = us;
                    }
                }
            }
        }
        __syncthreads();
        #pragma unroll
        for (int it = 0; it < 4; ++it) {
            int idx = it * 256 + tid;        // 0..1023
            int rl = idx >> 4, ch = idx & 15;
            ushort8v vv = *reinterpret_cast<const ushort8v*>(&ep[rl][ch * 8]);
            int grow = m0 + p * 64 + rl;
            int gcol = (n0 & 1023) + ch * 8;
            *reinterpret_cast<ushort8v*>(dstb + (int64_t)grow * 1024 + gcol) = vv;
        }
    }
}

// ---------------- chunked parallel scan (round-8 scalar forms, proven) ----------------
// c_t = f_t*c_{t-1} + (1-f_t)*u0_t. Chunk transfer: c_out = A*c_in + B.

__global__ void scan_phase1(const unsigned short* __restrict__ fb,
                            const float* __restrict__ u0f,
                            const unsigned short* __restrict__ u0b, int useU0b,
                            float* __restrict__ Aout, float* __restrict__ Bout) {
    int t = blockIdx.x * blockDim.x + threadIdx.x;   // chunk*NBD + idx
    int idx = t & (NBD - 1);
    int chunk = t >> 15;
    int64_t base = (int64_t)chunk * CLEN * NBD + idx;
    float Ap = 1.0f, Bv = 0.0f;
    if (useU0b) {
        #pragma unroll 8
        for (int i = 0; i < CLEN; ++i, base += NBD) {
            float f = bf2f(fb[base]);
            float u0 = bf2f(u0b[base]);
            Bv = u0 + f * (Bv - u0);
            Ap *= f;
        }
    } else {
        #pragma unroll 8
        for (int i = 0; i < CLEN; ++i, base += NBD) {
            float f = bf2f(fb[base]);
            float u0 = u0f[base];
            Bv = u0 + f * (Bv - u0);
            Ap *= f;
        }
    }
    Aout[t] = Ap; Bout[t] = Bv;
}

__global__ void scan_phase2(const float* __restrict__ c0, const float* __restrict__ Aarr,
                            const float* __restrict__ Barr, float* __restrict__ cin) {
    int idx = blockIdx.x * blockDim.x + threadIdx.x; // 0..NBD-1
    float c = c0[idx];
    #pragma unroll
    for (int ch = 0; ch < NCHUNK; ++ch) {
        cin[ch * NBD + idx] = c;
        c = Aarr[ch * NBD + idx] * c + Barr[ch * NBD + idx];
    }
}

__global__ void scan_phase3(const float* __restrict__ x,
                            const unsigned short* __restrict__ fb,
                            const unsigned short* __restrict__ rb,
                            const unsigned short* __restrict__ u0b, int useU0b,
                            const float* __restrict__ cin,
                            float* __restrict__ out_h, float* __restrict__ out_c) {
    int t = blockIdx.x * blockDim.x + threadIdx.x;
    int idx = t & (NBD - 1);
    int chunk = t >> 15;
    float c = cin[t];
    int64_t base = (int64_t)chunk * CLEN * NBD + idx;
    if (useU0b) {
        #pragma unroll 4
        for (int i = 0; i < CLEN; ++i, base += NBD) {
            float f  = bf2f(fb[base]);
            float u0 = bf2f(u0b[base]);
            c = u0 + f * (c - u0);      // f*c + (1-f)*u0
            out_c[base] = c;
            float e = __expf(2.0f * c);
            float g = (e - 1.0f) / (e + 1.0f);
            float r = bf2f(rb[base]);
            float xv = x[base];
            out_h[base] = xv + r * (g - xv);
        }
    } else {
        #pragma unroll 4
        for (int i = 0; i < CLEN; ++i, base += NBD) {
            float f  = bf2f(fb[base]);
            float u0 = out_c[base];     // u0 written by gemm epilogue (in-place)
            c = u0 + f * (c - u0);
            out_c[base] = c;
            float e = __expf(2.0f * c);
            float g = (e - 1.0f) / (e + 1.0f);
            float r = bf2f(rb[base]);
            float xv = x[base];
            out_h[base] = xv + r * (g - xv);
        }
    }
}

extern "C" void kernel_launch(void* const* d_in, const int* in_sizes, int n_in,
                              void* d_out, int out_size, void* d_ws, size_t ws_size,
                              hipStream_t stream) {
    const float* x    = (const float*)d_in[0];
    const float* c0   = (const float*)d_in[1];
    const float* wgt  = (const float*)d_in[2];
    const float* bias = (const float*)d_in[3];
    float* out = (float*)d_out;

    unsigned short* xb = (unsigned short*)d_ws;                 // 64 MiB (dead after gemm)
    unsigned short* wT = xb + (int64_t)M_DIM * K_DIM;           // +6 MiB
    unsigned short* fb = wT + (int64_t)N3_DIM * K_DIM;          // +64 MiB, f bf16
    unsigned short* rb = fb + LBD;                              // +64 MiB, r bf16
    size_t need = ((size_t)M_DIM * K_DIM + (size_t)N3_DIM * K_DIM + 3 * (size_t)LBD) * 2;
    int useU0b = (ws_size >= need) ? 1 : 0;
    unsigned short* u0b = useU0b ? (rb + LBD) : nullptr;

    // A/B/cin overlay the xb region (xb is dead once gemm completes)
    float* Aarr = (float*)d_ws;                                 // 4 MiB
    float* Barr = Aarr + NCHUNK * NBD;                          // 4 MiB
    float* cin  = Barr + NCHUNK * NBD;                          // 4 MiB

    cvt_kernel<<<4864, 256, 0, stream>>>(x, xb, wgt, wT);
    gemm_kernel<<<NMT * NNT, 256, 0, stream>>>(xb, wT, bias, out + LBD, fb, rb, u0b, useU0b);
    scan_phase1<<<(NCHUNK * NBD) / 256, 256, 0, stream>>>(fb, out + LBD, u0b, useU0b, Aarr, Barr);
    scan_phase2<<<NBD / 256, 256, 0, stream>>>(c0, Aarr, Barr, cin);
    scan_phase3<<<(NCHUNK * NBD) / 256, 256, 0, stream>>>(x, fb, rb, u0b, useU0b, cin, out, out + LBD);
}

// Round 11
// 473.932 us; speedup vs baseline: 1.0230x; 1.0230x over previous
//
#include <hip/hip_runtime.h>
#include <hip/hip_bf16.h>
#include <stdint.h>

#define L_DIM 1024
#define B_DIM 32
#define D_DIM 1024
#define M_DIM (L_DIM * B_DIM)        // 32768 GEMM rows
#define N3_DIM (3 * D_DIM)           // 3072 GEMM cols (u0 | f | r regions)
#define K_DIM D_DIM                  // 1024
#define LBD ((int64_t)L_DIM * B_DIM * D_DIM)  // 33554432
#define NBD (B_DIM * D_DIM)          // 32768 chains
#define NCHUNK 32
#define CLEN 32

// GEMM tiling: m97 geometry + swizzle + TLP (round-7/8 proven)
#define BM 128
#define BN 128
#define BK 64
#define NMT (M_DIM / BM)   // 256
#define NNT (N3_DIM / BN)  // 24
#define NKT (K_DIM / BK)   // 16

typedef __bf16 bf16_t;
typedef bf16_t bf16x8 __attribute__((ext_vector_type(8)));
typedef float f32x4 __attribute__((ext_vector_type(4)));
typedef unsigned short ushort8v __attribute__((ext_vector_type(8)));

// RTNE fp32 -> bf16 bits
__device__ __forceinline__ unsigned short f2bf(float f) {
    union { float f; unsigned u; } v; v.f = f;
    unsigned u = v.u;
    u += 0x7FFFu + ((u >> 16) & 1u);
    return (unsigned short)(u >> 16);
}
__device__ __forceinline__ float bf2f(unsigned short h) {
    union { unsigned u; float f; } v; v.u = ((unsigned)h) << 16;
    return v.f;
}

// ---------------- fused converts: x fp32->bf16 (blocks 0..4095), weight permute (blocks 4096..4863) ----------------
__global__ void cvt_kernel(const float* __restrict__ x, unsigned short* __restrict__ xb,
                           const float* __restrict__ w, unsigned short* __restrict__ wT) {
    __shared__ float tile[64][65];
    int bid = blockIdx.x;
    if (bid < 4096) {
        int64_t i0 = ((int64_t)bid * blockDim.x + threadIdx.x) * 8;
        const int64_t stride = (int64_t)4096 * 256 * 8;   // covers LBD in 4 iters
        for (int64_t i = i0; i < LBD; i += stride) {
            float4 v0 = *reinterpret_cast<const float4*>(x + i);
            float4 v1 = *reinterpret_cast<const float4*>(x + i + 4);
            ushort8v o;
            o[0] = f2bf(v0.x); o[1] = f2bf(v0.y); o[2] = f2bf(v0.z); o[3] = f2bf(v0.w);
            o[4] = f2bf(v1.x); o[5] = f2bf(v1.y); o[6] = f2bf(v1.z); o[7] = f2bf(v1.w);
            *reinterpret_cast<ushort8v*>(xb + i) = o;
        }
    } else {
        int wb = bid - 4096;            // 768 = 3(k) * 16(o-tiles) * 16(i-tiles)
        int k  = wb >> 8;
        int o0 = ((wb >> 4) & 15) * 64;
        int i0 = (wb & 15) * 64;
        int t = threadIdx.x;
        {
            int o = t & 63, ib = t >> 6;
            #pragma unroll
            for (int it = 0; it < 16; ++it) {
                int i = ib + it * 4;
                tile[o][i] = w[((int64_t)(i0 + i) * 1024 + (o0 + o)) * 3 + k];
            }
        }
        __syncthreads();
        {
            int i = t & 63, ob = t >> 6;
            #pragma unroll
            for (int ot = 0; ot < 16; ++ot) {
                int o = ob + ot * 4;
                wT[(int64_t)(k * 1024 + o0 + o) * 1024 + (i0 + i)] = f2bf(tile[o][i]);
            }
        }
    }
}

// ---------------- GEMM: m97 2-barrier loop, 128x128, 4 waves, swizzled LDS, XCD mt-banding ----------------
__device__ __forceinline__ void gload_lds16(const void* g, void* l) {
    __builtin_amdgcn_global_load_lds(
        (const __attribute__((address_space(1))) unsigned int*)g,
        (__attribute__((address_space(3))) unsigned int*)l,
        16, 0, 0);
}

__global__ __launch_bounds__(256, 4) void gemm_kernel(
    const unsigned short* __restrict__ A,    // [32768][1024] bf16 bits
    const unsigned short* __restrict__ Bt,   // [3072][1024] bf16 bits
    const float* __restrict__ bias,          // [2048]
    float* __restrict__ u0_out,              // d_out + LBD: u0 fp32 (fallback path)
    unsigned short* __restrict__ fb,         // ws: f bf16
    unsigned short* __restrict__ rb,         // ws: r bf16
    unsigned short* __restrict__ u0b,        // ws: u0 bf16 (fast path) or null
    int useU0b)
{
    __shared__ __align__(16) unsigned short a_tile[128 * 64];
    __shared__ __align__(16) unsigned short b_tile[128 * 64];

    int bid = blockIdx.x;
    // XCD mt-banding: each XCD owns 32 consecutive A-panels; nt iterates fast, so
    // the A-panel (256 KB) stays L2-resident across 24 consecutive blocks (fetched ~once)
    // and B (6 MB total) is L2-resident per XCD.
    int xcd = bid & 7, local = bid >> 3;           // 768 blocks per XCD
    int mt = xcd * 32 + local / NNT;
    int nt = local % NNT;
    int m0 = mt * BM, n0 = nt * BN;

    int tid = threadIdx.x;
    int w = tid >> 6, lane = tid & 63;
    int wr = (w >> 1) * 64, wc = (w & 1) * 64;     // 2x2 wave grid, 64x64 per wave
    int l15 = lane & 15, l4 = lane >> 4;
    int pcx = l15 & 7;                             // read-side XOR (row&7)

    int sr = lane >> 3;                            // row within 8-row group (= row&7)
    int sc = ((lane & 7) ^ sr) << 3;               // swizzled 16B chunk in bf16 elems
    const unsigned short* Abase = A  + (int64_t)(m0 + sr) * K_DIM + sc;
    const unsigned short* Bbase = Bt + (int64_t)(n0 + sr) * K_DIM + sc;

    f32x4 acc[4][4];
    #pragma unroll
    for (int i = 0; i < 4; ++i)
        #pragma unroll
        for (int j = 0; j < 4; ++j) acc[i][j] = (f32x4){0.f, 0.f, 0.f, 0.f};

    for (int kt = 0; kt < NKT; ++kt) {
        int k0 = kt * BK;
        __syncthreads();
        #pragma unroll
        for (int i = 0; i < 4; ++i) {
            int r0 = (i * 4 + w) * 8;
            gload_lds16(Abase + (int64_t)r0 * K_DIM + k0, &a_tile[r0 * 64]);
            gload_lds16(Bbase + (int64_t)r0 * K_DIM + k0, &b_tile[r0 * 64]);
        }
        __syncthreads();

        #pragma unroll
        for (int ks = 0; ks < 2; ++ks) {
            int pc = ((ks * 4 + l4) ^ pcx) << 3;
            bf16x8 af[4], bf[4];
            #pragma unroll
            for (int im = 0; im < 4; ++im)
                af[im] = *reinterpret_cast<const bf16x8*>(&a_tile[(wr + im * 16 + l15) * 64 + pc]);
            #pragma unroll
            for (int jn = 0; jn < 4; ++jn)
                bf[jn] = *reinterpret_cast<const bf16x8*>(&b_tile[(wc + jn * 16 + l15) * 64 + pc]);
            #pragma unroll
            for (int im = 0; im < 4; ++im)
                #pragma unroll
                for (int jn = 0; jn < 4; ++jn)
                    acc[im][jn] = __builtin_amdgcn_mfma_f32_16x16x32_bf16(
                        af[im], bf[jn], acc[im][jn], 0, 0, 0);
        }
    }

    // epilogue: direct scatter (round-8 proven; LDS staging regressed in round 10)
    int region = n0 >> 10;
    #pragma unroll
    for (int im = 0; im < 4; ++im) {
        #pragma unroll
        for (int jn = 0; jn < 4; ++jn) {
            f32x4 v = acc[im][jn];
            int row0 = m0 + wr + im * 16 + l4 * 4;
            int col  = (n0 + wc + jn * 16 + l15) & 1023;
            #pragma unroll
            for (int jj = 0; jj < 4; ++jj) {
                int64_t idx = (int64_t)(row0 + jj) * 1024 + col;
                float val = v[jj];
                if (region == 0) {
                    if (useU0b) u0b[idx] = f2bf(val);
                    else        u0_out[idx] = val;
                } else if (region == 1) {
                    fb[idx] = f2bf(1.0f / (1.0f + __expf(-(val + bias[col]))));
                } else {
                    rb[idx] = f2bf(1.0f / (1.0f + __expf(-(val + bias[1024 + col]))));
                }
            }
        }
    }
}

// ---------------- chunked parallel scan (round-8 scalar forms, proven) ----------------
// c_t = f_t*c_{t-1} + (1-f_t)*u0_t. Chunk transfer: c_out = A*c_in + B.

__global__ void scan_phase1(const unsigned short* __restrict__ fb,
                            const float* __restrict__ u0f,
                            const unsigned short* __restrict__ u0b, int useU0b,
                            float* __restrict__ Aout, float* __restrict__ Bout) {
    int t = blockIdx.x * blockDim.x + threadIdx.x;   // chunk*NBD + idx
    int idx = t & (NBD - 1);
    int chunk = t >> 15;
    int64_t base = (int64_t)chunk * CLEN * NBD + idx;
    float Ap = 1.0f, Bv = 0.0f;
    if (useU0b) {
        #pragma unroll 8
        for (int i = 0; i < CLEN; ++i, base += NBD) {
            float f = bf2f(fb[base]);
            float u0 = bf2f(u0b[base]);
            Bv = u0 + f * (Bv - u0);
            Ap *= f;
        }
    } else {
        #pragma unroll 8
        for (int i = 0; i < CLEN; ++i, base += NBD) {
            float f = bf2f(fb[base]);
            float u0 = u0f[base];
            Bv = u0 + f * (Bv - u0);
            Ap *= f;
        }
    }
    Aout[t] = Ap; Bout[t] = Bv;
}

__global__ void scan_phase2(const float* __restrict__ c0, const float* __restrict__ Aarr,
                            const float* __restrict__ Barr, float* __restrict__ cin) {
    int idx = blockIdx.x * blockDim.x + threadIdx.x; // 0..NBD-1
    float c = c0[idx];
    #pragma unroll
    for (int ch = 0; ch < NCHUNK; ++ch) {
        cin[ch * NBD + idx] = c;
        c = Aarr[ch * NBD + idx] * c + Barr[ch * NBD + idx];
    }
}

__global__ void scan_phase3(const float* __restrict__ x,
                            const unsigned short* __restrict__ xb, int useXb,
                            const unsigned short* __restrict__ fb,
                            const unsigned short* __restrict__ rb,
                            const unsigned short* __restrict__ u0b, int useU0b,
                            const float* __restrict__ cin,
                            float* __restrict__ out_h, float* __restrict__ out_c) {
    int t = blockIdx.x * blockDim.x + threadIdx.x;
    int idx = t & (NBD - 1);
    int chunk = t >> 15;
    float c = cin[t];
    int64_t base = (int64_t)chunk * CLEN * NBD + idx;
    if (useU0b && useXb) {
        #pragma unroll 4
        for (int i = 0; i < CLEN; ++i, base += NBD) {
            float f  = bf2f(fb[base]);
            float u0 = bf2f(u0b[base]);
            c = u0 + f * (c - u0);      // f*c + (1-f)*u0
            out_c[base] = c;
            float e = __expf(2.0f * c);
            float g = (e - 1.0f) / (e + 1.0f);
            float r = bf2f(rb[base]);
            float xv = bf2f(xb[base]);  // bf16 x: saves 67 MB of fp32 reads
            out_h[base] = xv + r * (g - xv);
        }
    } else if (useU0b) {
        #pragma unroll 4
        for (int i = 0; i < CLEN; ++i, base += NBD) {
            float f  = bf2f(fb[base]);
            float u0 = bf2f(u0b[base]);
            c = u0 + f * (c - u0);
            out_c[base] = c;
            float e = __expf(2.0f * c);
            float g = (e - 1.0f) / (e + 1.0f);
            float r = bf2f(rb[base]);
            float xv = x[base];
            out_h[base] = xv + r * (g - xv);
        }
    } else {
        #pragma unroll 4
        for (int i = 0; i < CLEN; ++i, base += NBD) {
            float f  = bf2f(fb[base]);
            float u0 = out_c[base];     // u0 written by gemm epilogue (in-place)
            c = u0 + f * (c - u0);
            out_c[base] = c;
            float e = __expf(2.0f * c);
            float g = (e - 1.0f) / (e + 1.0f);
            float r = bf2f(rb[base]);
            float xv = x[base];
            out_h[base] = xv + r * (g - xv);
        }
    }
}

extern "C" void kernel_launch(void* const* d_in, const int* in_sizes, int n_in,
                              void* d_out, int out_size, void* d_ws, size_t ws_size,
                              hipStream_t stream) {
    const float* x    = (const float*)d_in[0];
    const float* c0   = (const float*)d_in[1];
    const float* wgt  = (const float*)d_in[2];
    const float* bias = (const float*)d_in[3];
    float* out = (float*)d_out;

    unsigned short* xb = (unsigned short*)d_ws;                 // 64 MiB
    unsigned short* wT = xb + (int64_t)M_DIM * K_DIM;           // +6 MiB
    unsigned short* fb = wT + (int64_t)N3_DIM * K_DIM;          // +64 MiB, f bf16
    unsigned short* rb = fb + LBD;                              // +64 MiB, r bf16

    size_t base_elems = (size_t)M_DIM * K_DIM + (size_t)N3_DIM * K_DIM + 3 * (size_t)LBD;
    size_t need1 = base_elems * 2;                              // u0b fits
    size_t need2 = need1 + (size_t)3 * NCHUNK * NBD * 4;        // + A/B/cin after u0b
    int useU0b = (ws_size >= need1) ? 1 : 0;
    unsigned short* u0b = useU0b ? (rb + LBD) : nullptr;
    int useXb = (useU0b && ws_size >= need2) ? 1 : 0;

    float* Aarr, *Barr, *cin;
    if (useXb) {
        // place scan temporaries after u0b; xb stays live for phase3
        Aarr = (float*)(u0b + LBD);
        Barr = Aarr + NCHUNK * NBD;
        cin  = Barr + NCHUNK * NBD;
    } else {
        // overlay the xb region (xb dead after gemm)
        Aarr = (float*)d_ws;
        Barr = Aarr + NCHUNK * NBD;
        cin  = Barr + NCHUNK * NBD;
    }

    cvt_kernel<<<4864, 256, 0, stream>>>(x, xb, wgt, wT);
    gemm_kernel<<<NMT * NNT, 256, 0, stream>>>(xb, wT, bias, out + LBD, fb, rb, u0b, useU0b);
    scan_phase1<<<(NCHUNK * NBD) / 256, 256, 0, stream>>>(fb, out + LBD, u0b, useU0b, Aarr, Barr);
    scan_phase2<<<NBD / 256, 256, 0, stream>>>(c0, Aarr, Barr, cin);
    scan_phase3<<<(NCHUNK * NBD) / 256, 256, 0, stream>>>(x, xb, useXb, fb, rb, u0b, useU0b, cin, out, out + LBD);
}

// Round 12
// 458.550 us; speedup vs baseline: 1.0573x; 1.0335x over previous
//
#include <hip/hip_runtime.h>
#include <hip/hip_bf16.h>
#include <stdint.h>

#define L_DIM 1024
#define B_DIM 32
#define D_DIM 1024
#define M_DIM (L_DIM * B_DIM)        // 32768 GEMM rows
#define N3_DIM (3 * D_DIM)           // 3072 GEMM cols (u0 | f | r regions)
#define K_DIM D_DIM                  // 1024
#define LBD ((int64_t)L_DIM * B_DIM * D_DIM)  // 33554432
#define NBD (B_DIM * D_DIM)          // 32768 chains
#define NCHUNK 32
#define CLEN 32

// GEMM tiling: m97 geometry + swizzle + TLP (round-7/8 proven)
#define BM 128
#define BN 128
#define BK 64
#define NMT (M_DIM / BM)   // 256
#define NNT (N3_DIM / BN)  // 24
#define NKT (K_DIM / BK)   // 16

typedef __bf16 bf16_t;
typedef bf16_t bf16x8 __attribute__((ext_vector_type(8)));
typedef float f32x4 __attribute__((ext_vector_type(4)));
typedef unsigned short ushort8v __attribute__((ext_vector_type(8)));

// RTNE fp32 -> bf16 bits
__device__ __forceinline__ unsigned short f2bf(float f) {
    union { float f; unsigned u; } v; v.f = f;
    unsigned u = v.u;
    u += 0x7FFFu + ((u >> 16) & 1u);
    return (unsigned short)(u >> 16);
}
__device__ __forceinline__ float bf2f(unsigned short h) {
    union { unsigned u; float f; } v; v.u = ((unsigned)h) << 16;
    return v.f;
}

// ---------------- fused converts: x fp32->bf16 (blocks 0..4095), weight permute (blocks 4096..4863) ----------------
__global__ void cvt_kernel(const float* __restrict__ x, unsigned short* __restrict__ xb,
                           const float* __restrict__ w, unsigned short* __restrict__ wT) {
    __shared__ float tile[64][65];
    int bid = blockIdx.x;
    if (bid < 4096) {
        int64_t i0 = ((int64_t)bid * blockDim.x + threadIdx.x) * 8;
        const int64_t stride = (int64_t)4096 * 256 * 8;   // covers LBD in 4 iters
        for (int64_t i = i0; i < LBD; i += stride) {
            float4 v0 = *reinterpret_cast<const float4*>(x + i);
            float4 v1 = *reinterpret_cast<const float4*>(x + i + 4);
            ushort8v o;
            o[0] = f2bf(v0.x); o[1] = f2bf(v0.y); o[2] = f2bf(v0.z); o[3] = f2bf(v0.w);
            o[4] = f2bf(v1.x); o[5] = f2bf(v1.y); o[6] = f2bf(v1.z); o[7] = f2bf(v1.w);
            *reinterpret_cast<ushort8v*>(xb + i) = o;
        }
    } else {
        int wb = bid - 4096;            // 768 = 3(k) * 16(o-tiles) * 16(i-tiles)
        int k  = wb >> 8;
        int o0 = ((wb >> 4) & 15) * 64;
        int i0 = (wb & 15) * 64;
        int t = threadIdx.x;
        {
            int o = t & 63, ib = t >> 6;
            #pragma unroll
            for (int it = 0; it < 16; ++it) {
                int i = ib + it * 4;
                tile[o][i] = w[((int64_t)(i0 + i) * 1024 + (o0 + o)) * 3 + k];
            }
        }
        __syncthreads();
        {
            int i = t & 63, ob = t >> 6;
            #pragma unroll
            for (int ot = 0; ot < 16; ++ot) {
                int o = ob + ot * 4;
                wT[(int64_t)(k * 1024 + o0 + o) * 1024 + (i0 + i)] = f2bf(tile[o][i]);
            }
        }
    }
}

// ---------------- GEMM: m97 2-barrier loop, 128x128, 4 waves, swizzled LDS, XCD nt-banding ----------------
__device__ __forceinline__ void gload_lds16(const void* g, void* l) {
    __builtin_amdgcn_global_load_lds(
        (const __attribute__((address_space(1))) unsigned int*)g,
        (__attribute__((address_space(3))) unsigned int*)l,
        16, 0, 0);
}

__global__ __launch_bounds__(256, 4) void gemm_kernel(
    const unsigned short* __restrict__ A,    // [32768][1024] bf16 bits
    const unsigned short* __restrict__ Bt,   // [3072][1024] bf16 bits
    const float* __restrict__ bias,          // [2048]
    float* __restrict__ u0_out,              // d_out + LBD: u0 fp32 (fallback path)
    unsigned short* __restrict__ fb,         // ws: f bf16
    unsigned short* __restrict__ rb,         // ws: r bf16
    unsigned short* __restrict__ u0b,        // ws: u0 bf16 (fast path) or null
    int useU0b)
{
    __shared__ __align__(16) unsigned short a_tile[128 * 64];
    __shared__ __align__(16) unsigned short b_tile[128 * 64];

    int bid = blockIdx.x;
    // round-8 proven mapping: each XCD owns 3 n-tiles (B slab 0.75 MB, L2-resident);
    // consecutive blocks within an XCD share mt (A-panel read concurrently; L3 absorbs cross-XCD).
    int xcd = bid & 7, local = bid >> 3;           // 768 blocks per XCD
    int nt = xcd * 3 + (local % 3);
    int mt = local / 3;
    int m0 = mt * BM, n0 = nt * BN;

    int tid = threadIdx.x;
    int w = tid >> 6, lane = tid & 63;
    int wr = (w >> 1) * 64, wc = (w & 1) * 64;     // 2x2 wave grid, 64x64 per wave
    int l15 = lane & 15, l4 = lane >> 4;
    int pcx = l15 & 7;                             // read-side XOR (row&7)

    int sr = lane >> 3;                            // row within 8-row group (= row&7)
    int sc = ((lane & 7) ^ sr) << 3;               // swizzled 16B chunk in bf16 elems
    const unsigned short* Abase = A  + (int64_t)(m0 + sr) * K_DIM + sc;
    const unsigned short* Bbase = Bt + (int64_t)(n0 + sr) * K_DIM + sc;

    f32x4 acc[4][4];
    #pragma unroll
    for (int i = 0; i < 4; ++i)
        #pragma unroll
        for (int j = 0; j < 4; ++j) acc[i][j] = (f32x4){0.f, 0.f, 0.f, 0.f};

    for (int kt = 0; kt < NKT; ++kt) {
        int k0 = kt * BK;
        __syncthreads();
        #pragma unroll
        for (int i = 0; i < 4; ++i) {
            int r0 = (i * 4 + w) * 8;
            gload_lds16(Abase + (int64_t)r0 * K_DIM + k0, &a_tile[r0 * 64]);
            gload_lds16(Bbase + (int64_t)r0 * K_DIM + k0, &b_tile[r0 * 64]);
        }
        __syncthreads();

        #pragma unroll
        for (int ks = 0; ks < 2; ++ks) {
            int pc = ((ks * 4 + l4) ^ pcx) << 3;
            bf16x8 af[4], bf[4];
            #pragma unroll
            for (int im = 0; im < 4; ++im)
                af[im] = *reinterpret_cast<const bf16x8*>(&a_tile[(wr + im * 16 + l15) * 64 + pc]);
            #pragma unroll
            for (int jn = 0; jn < 4; ++jn)
                bf[jn] = *reinterpret_cast<const bf16x8*>(&b_tile[(wc + jn * 16 + l15) * 64 + pc]);
            #pragma unroll
            for (int im = 0; im < 4; ++im)
                #pragma unroll
                for (int jn = 0; jn < 4; ++jn)
                    acc[im][jn] = __builtin_amdgcn_mfma_f32_16x16x32_bf16(
                        af[im], bf[jn], acc[im][jn], 0, 0, 0);
        }
    }

    // epilogue: direct scatter (round-8 proven)
    int region = n0 >> 10;
    #pragma unroll
    for (int im = 0; im < 4; ++im) {
        #pragma unroll
        for (int jn = 0; jn < 4; ++jn) {
            f32x4 v = acc[im][jn];
            int row0 = m0 + wr + im * 16 + l4 * 4;
            int col  = (n0 + wc + jn * 16 + l15) & 1023;
            #pragma unroll
            for (int jj = 0; jj < 4; ++jj) {
                int64_t idx = (int64_t)(row0 + jj) * 1024 + col;
                float val = v[jj];
                if (region == 0) {
                    if (useU0b) u0b[idx] = f2bf(val);
                    else        u0_out[idx] = val;
                } else if (region == 1) {
                    fb[idx] = f2bf(1.0f / (1.0f + __expf(-(val + bias[col]))));
                } else {
                    rb[idx] = f2bf(1.0f / (1.0f + __expf(-(val + bias[1024 + col]))));
                }
            }
        }
    }
}

// ---------------- chunked parallel scan (round-8 scalar forms, proven) ----------------
// c_t = f_t*c_{t-1} + (1-f_t)*u0_t. Chunk transfer: c_out = A*c_in + B.

__global__ void scan_phase1(const unsigned short* __restrict__ fb,
                            const float* __restrict__ u0f,
                            const unsigned short* __restrict__ u0b, int useU0b,
                            float* __restrict__ Aout, float* __restrict__ Bout) {
    int t = blockIdx.x * blockDim.x + threadIdx.x;   // chunk*NBD + idx
    int idx = t & (NBD - 1);
    int chunk = t >> 15;
    int64_t base = (int64_t)chunk * CLEN * NBD + idx;
    float Ap = 1.0f, Bv = 0.0f;
    if (useU0b) {
        #pragma unroll 8
        for (int i = 0; i < CLEN; ++i, base += NBD) {
            float f = bf2f(fb[base]);
            float u0 = bf2f(u0b[base]);
            Bv = u0 + f * (Bv - u0);
            Ap *= f;
        }
    } else {
        #pragma unroll 8
        for (int i = 0; i < CLEN; ++i, base += NBD) {
            float f = bf2f(fb[base]);
            float u0 = u0f[base];
            Bv = u0 + f * (Bv - u0);
            Ap *= f;
        }
    }
    Aout[t] = Ap; Bout[t] = Bv;
}

__global__ void scan_phase2(const float* __restrict__ c0, const float* __restrict__ Aarr,
                            const float* __restrict__ Barr, float* __restrict__ cin) {
    int idx = blockIdx.x * blockDim.x + threadIdx.x; // 0..NBD-1
    float c = c0[idx];
    #pragma unroll
    for (int ch = 0; ch < NCHUNK; ++ch) {
        cin[ch * NBD + idx] = c;
        c = Aarr[ch * NBD + idx] * c + Barr[ch * NBD + idx];
    }
}

__global__ void scan_phase3(const float* __restrict__ x,
                            const unsigned short* __restrict__ xb, int useXb,
                            const unsigned short* __restrict__ fb,
                            const unsigned short* __restrict__ rb,
                            const unsigned short* __restrict__ u0b, int useU0b,
                            const float* __restrict__ cin,
                            float* __restrict__ out_h, float* __restrict__ out_c) {
    int t = blockIdx.x * blockDim.x + threadIdx.x;
    int idx = t & (NBD - 1);
    int chunk = t >> 15;
    float c = cin[t];
    int64_t base = (int64_t)chunk * CLEN * NBD + idx;
    if (useU0b && useXb) {
        #pragma unroll 4
        for (int i = 0; i < CLEN; ++i, base += NBD) {
            float f  = bf2f(fb[base]);
            float u0 = bf2f(u0b[base]);
            c = u0 + f * (c - u0);      // f*c + (1-f)*u0
            out_c[base] = c;
            float e = __expf(2.0f * c);
            float g = (e - 1.0f) / (e + 1.0f);
            float r = bf2f(rb[base]);
            float xv = bf2f(xb[base]);  // bf16 x: saves 67 MB of fp32 reads
            out_h[base] = xv + r * (g - xv);
        }
    } else if (useU0b) {
        #pragma unroll 4
        for (int i = 0; i < CLEN; ++i, base += NBD) {
            float f  = bf2f(fb[base]);
            float u0 = bf2f(u0b[base]);
            c = u0 + f * (c - u0);
            out_c[base] = c;
            float e = __expf(2.0f * c);
            float g = (e - 1.0f) / (e + 1.0f);
            float r = bf2f(rb[base]);
            float xv = x[base];
            out_h[base] = xv + r * (g - xv);
        }
    } else {
        #pragma unroll 4
        for (int i = 0; i < CLEN; ++i, base += NBD) {
            float f  = bf2f(fb[base]);
            float u0 = out_c[base];     // u0 written by gemm epilogue (in-place)
            c = u0 + f * (c - u0);
            out_c[base] = c;
            float e = __expf(2.0f * c);
            float g = (e - 1.0f) / (e + 1.0f);
            float r = bf2f(rb[base]);
            float xv = x[base];
            out_h[base] = xv + r * (g - xv);
        }
    }
}

extern "C" void kernel_launch(void* const* d_in, const int* in_sizes, int n_in,
                              void* d_out, int out_size, void* d_ws, size_t ws_size,
                              hipStream_t stream) {
    const float* x    = (const float*)d_in[0];
    const float* c0   = (const float*)d_in[1];
    const float* wgt  = (const float*)d_in[2];
    const float* bias = (const float*)d_in[3];
    float* out = (float*)d_out;

    unsigned short* xb = (unsigned short*)d_ws;                 // 64 MiB
    unsigned short* wT = xb + (int64_t)M_DIM * K_DIM;           // +6 MiB
    unsigned short* fb = wT + (int64_t)N3_DIM * K_DIM;          // +64 MiB, f bf16
    unsigned short* rb = fb + LBD;                              // +64 MiB, r bf16

    size_t base_elems = (size_t)M_DIM * K_DIM + (size_t)N3_DIM * K_DIM + 3 * (size_t)LBD;
    size_t need1 = base_elems * 2;                              // u0b fits
    size_t need2 = need1 + (size_t)3 * NCHUNK * NBD * 4;        // + A/B/cin after u0b
    int useU0b = (ws_size >= need1) ? 1 : 0;
    unsigned short* u0b = useU0b ? (rb + LBD) : nullptr;
    int useXb = (useU0b && ws_size >= need2) ? 1 : 0;

    float* Aarr, *Barr, *cin;
    if (useXb) {
        // place scan temporaries after u0b; xb stays live for phase3
        Aarr = (float*)(u0b + LBD);
        Barr = Aarr + NCHUNK * NBD;
        cin  = Barr + NCHUNK * NBD;
    } else {
        // overlay the xb region (xb dead after gemm)
        Aarr = (float*)d_ws;
        Barr = Aarr + NCHUNK * NBD;
        cin  = Barr + NCHUNK * NBD;
    }

    cvt_kernel<<<4864, 256, 0, stream>>>(x, xb, wgt, wT);
    gemm_kernel<<<NMT * NNT, 256, 0, stream>>>(xb, wT, bias, out + LBD, fb, rb, u0b, useU0b);
    scan_phase1<<<(NCHUNK * NBD) / 256, 256, 0, stream>>>(fb, out + LBD, u0b, useU0b, Aarr, Barr);
    scan_phase2<<<NBD / 256, 256, 0, stream>>>(c0, Aarr, Barr, cin);
    scan_phase3<<<(NCHUNK * NBD) / 256, 256, 0, stream>>>(x, xb, useXb, fb, rb, u0b, useU0b, cin, out, out + LBD);
}